// Round 1
// baseline (5182.834 us; speedup 1.0000x reference)
//
#include <hip/hip_runtime.h>

#define NN 50000
#define NE 1000000
#define CC 64
#define LL 16
#define KSEL 512
#define HIDD 1024
#define FULLW 1152
#define EPSV 1e-5f

// ---------------- CSR build ----------------

__global__ __launch_bounds__(256) void hist_kernel(const int* __restrict__ src,
    const int* __restrict__ dst, int* __restrict__ cnt_in, int* __restrict__ cnt_out) {
  int stride = gridDim.x * blockDim.x;
  for (int e = blockIdx.x * blockDim.x + threadIdx.x; e < NE; e += stride) {
    atomicAdd(&cnt_in[dst[e]], 1);
    atomicAdd(&cnt_out[src[e]], 1);
  }
}

__global__ __launch_bounds__(1024) void scan_kernel(const int* __restrict__ cnt,
    int* __restrict__ rp) {
  // blockIdx.x = 0: in, 1: out
  const int* c = cnt + blockIdx.x * NN;
  int* r = rp + blockIdx.x * (NN + 1);
  __shared__ int part[1024];
  int t = threadIdx.x;
  const int CH = (NN + 1023) / 1024;
  int beg = t * CH;
  int end = min(beg + CH, NN);
  int s = 0;
  for (int i = beg; i < end; ++i) s += c[i];
  part[t] = s;
  __syncthreads();
  if (t == 0) {
    int run = 0;
    for (int i = 0; i < 1024; ++i) { int v = part[i]; part[i] = run; run += v; }
  }
  __syncthreads();
  int off = part[t];
  for (int i = beg; i < end; ++i) { r[i] = off; off += c[i]; }
  if (t == 1023) r[NN] = off;
}

__global__ __launch_bounds__(256) void initcur_kernel(const int* __restrict__ rp_in,
    const int* __restrict__ rp_out, int* __restrict__ cur_in, int* __restrict__ cur_out,
    float* __restrict__ statsA) {
  int i = blockIdx.x * 256 + threadIdx.x;
  if (i < NN) cur_in[i] = rp_in[i];
  else if (i < 2 * NN) cur_out[i - NN] = rp_out[i - NN];
  if (blockIdx.x == 0 && threadIdx.x < 128) statsA[threadIdx.x] = 0.f;
}

__global__ __launch_bounds__(256) void fill_kernel(const int* __restrict__ src,
    const int* __restrict__ dst, int* __restrict__ cur_in, int* __restrict__ cur_out,
    int* __restrict__ col_in, int* __restrict__ col_out) {
  int stride = gridDim.x * blockDim.x;
  for (int e = blockIdx.x * blockDim.x + threadIdx.x; e < NE; e += stride) {
    int s = src[e], d = dst[e];
    int p = atomicAdd(&cur_in[d], 1);
    col_in[p] = s;
    int q = atomicAdd(&cur_out[s], 1);
    col_out[q] = d;
  }
}

// ---------------- embedding + sel gather ----------------

__global__ __launch_bounds__(256) void embed_kernel(const int* __restrict__ nt,
    const float* __restrict__ emb, float* __restrict__ X) {
  int id = blockIdx.x * 256 + threadIdx.x;
  if (id >= NN * CC) return;
  X[id] = emb[nt[id >> 6] * CC + (id & 63)];
}

__global__ __launch_bounds__(256) void gather_sel_kernel(const float* __restrict__ xsrc,
    const int* __restrict__ idx, float* __restrict__ sel, int coloff) {
  int tid = blockIdx.x * 256 + threadIdx.x;
  if (tid >= KSEL * CC) return;
  int k = tid >> 6, cch = tid & 63;
  sel[k * FULLW + coloff + cch] = xsrc[idx[k] * CC + cch];
}

// ---------------- matmul: Y = f(X) @ W ----------------
// W layout [2][64][32]; output col j -> W[j>>5][c][j&31].
// f = BN(relu(.)) from stats (sum,sumsq) if stats!=null else identity.
// Block 0 zeroes stats_zero (the OTHER stats buffer) for the next producer.

__global__ __launch_bounds__(256) void mm_kernel(const float* __restrict__ X,
    float* __restrict__ Y, const float* __restrict__ W,
    const float* __restrict__ stats, const float* __restrict__ gamma,
    const float* __restrict__ beta, float* __restrict__ stats_zero) {
  int t = threadIdx.x;
  int lane = t & 63;
  int wid = t >> 6;
  float wreg[CC];
  {
    const float* wb = W + (lane >> 5) * 2048 + (lane & 31);
#pragma unroll
    for (int c2 = 0; c2 < CC; ++c2) wreg[c2] = wb[c2 * 32];
  }
  __shared__ float sc[CC], sh[CC];
  __shared__ __align__(16) float Xs[64][CC];
  if (t < CC) {
    float scale = 1.f, shift = 0.f;
    if (stats) {
      float m = stats[t] * (1.f / NN);
      float v = stats[CC + t] * (1.f / NN) - m * m;
      float is = rsqrtf(v + EPSV);
      scale = gamma[t] * is;
      shift = beta[t] - m * scale;
    }
    sc[t] = scale; sh[t] = shift;
  }
  if (stats_zero && blockIdx.x == 0 && t < 128) stats_zero[t] = 0.f;
  const bool bn = (stats != nullptr);
  for (int row0 = blockIdx.x * 64; row0 < NN; row0 += gridDim.x * 64) {
    int nrows = min(64, NN - row0);
    __syncthreads();
    for (int idx = t; idx < nrows * CC; idx += 256) {
      int r = idx >> 6, cch = idx & 63;
      float v = X[(row0 + r) * CC + cch];
      if (bn) { v = fmaxf(v, 0.f); v = v * sc[cch] + sh[cch]; }
      Xs[r][cch] = v;
    }
    __syncthreads();
    for (int r = wid; r < nrows; r += 4) {
      const float* xr = &Xs[r][0];
      float a0 = 0.f, a1 = 0.f, a2 = 0.f, a3 = 0.f;
#pragma unroll
      for (int c2 = 0; c2 < CC; c2 += 4) {
        float4 xv = *(const float4*)(xr + c2);
        a0 += xv.x * wreg[c2];
        a1 += xv.y * wreg[c2 + 1];
        a2 += xv.z * wreg[c2 + 2];
        a3 += xv.w * wreg[c2 + 3];
      }
      Y[(row0 + r) * CC + lane] = (a0 + a1) + (a2 + a3);
    }
  }
}

// ---------------- segment-sum (both directions) + optional skip + BN stats ----------------
// channels 0..31: sum over in-edges of Y[src][c]; 32..63: out-edges of Y[dst][c].

__global__ __launch_bounds__(256) void seg_kernel(
    const float* __restrict__ Y, const float* skip, float* OUT,
    const int* __restrict__ rp_in, const int* __restrict__ col_in,
    const int* __restrict__ rp_out, const int* __restrict__ col_out,
    float* __restrict__ stats_acc) {
  int t = threadIdx.x;
  int c = t & 63;
  int local = t >> 6;
  const int* rp = (c < 32) ? rp_in : rp_out;
  const int* col = (c < 32) ? col_in : col_out;
  float s1 = 0.f, s2 = 0.f;
  for (int i0 = blockIdx.x * 4; i0 < NN; i0 += gridDim.x * 4) {
    int i = i0 + local;
    if (i < NN) {
      int beg = rp[i], end = rp[i + 1];
      float a0 = 0.f, a1 = 0.f;
      int e = beg;
      for (; e + 2 <= end; e += 2) {
        int j0 = col[e], j1 = col[e + 1];
        a0 += Y[j0 * CC + c];
        a1 += Y[j1 * CC + c];
      }
      if (e < end) a0 += Y[col[e] * CC + c];
      float acc = a0 + a1;
      if (skip) acc += skip[i * CC + c];
      OUT[i * CC + c] = acc;
      float r = fmaxf(acc, 0.f);
      s1 += r; s2 += r * r;
    }
  }
  if (stats_acc) {
    __shared__ float red1[256], red2[256];
    red1[t] = s1; red2[t] = s2;
    __syncthreads();
    if (t < 64) {
      float v1 = red1[t] + red1[t + 64] + red1[t + 128] + red1[t + 192];
      float v2 = red2[t] + red2[t + 64] + red2[t + 128] + red2[t + 192];
      atomicAdd(&stats_acc[t], v1);
      atomicAdd(&stats_acc[CC + t], v2);
    }
  }
}

// ---------------- head ----------------

__global__ __launch_bounds__(64) void hidden_kernel(const float* __restrict__ sel,
    const float* __restrict__ Wh, const float* __restrict__ bh, float* __restrict__ h1) {
  int lane = threadIdx.x;
  int rb = blockIdx.x & 63;   // 64 row-blocks of 8 rows
  int jb = blockIdx.x >> 6;   // 16 col-blocks of 64 cols
  int j = jb * 64 + lane;
  int r0 = rb * 8;
  float acc[8];
#pragma unroll
  for (int r = 0; r < 8; ++r) acc[r] = 0.f;
  __shared__ __align__(16) float Ss[8][64];
  for (int k0 = 0; k0 < FULLW; k0 += 64) {
    float wreg[64];
#pragma unroll
    for (int c2 = 0; c2 < 64; ++c2) wreg[c2] = Wh[(k0 + c2) * HIDD + j];
    __syncthreads();
#pragma unroll
    for (int r = 0; r < 8; ++r) {
      float v = sel[(r0 + r) * FULLW + k0 + lane];
      Ss[r][lane] = fmaxf(v, 0.f);
    }
    __syncthreads();
#pragma unroll
    for (int r = 0; r < 8; ++r) {
      const float* sr = &Ss[r][0];
      float a0 = 0.f, a1 = 0.f, a2 = 0.f, a3 = 0.f;
#pragma unroll
      for (int c2 = 0; c2 < 64; c2 += 4) {
        float4 sv = *(const float4*)(sr + c2);
        a0 += sv.x * wreg[c2]; a1 += sv.y * wreg[c2 + 1];
        a2 += sv.z * wreg[c2 + 2]; a3 += sv.w * wreg[c2 + 3];
      }
      acc[r] += (a0 + a1) + (a2 + a3);
    }
  }
#pragma unroll
  for (int r = 0; r < 8; ++r) h1[(r0 + r) * HIDD + j] = acc[r] + bh[j];
}

__global__ __launch_bounds__(256) void out_kernel(const float* __restrict__ h1,
    const float* __restrict__ ow, const float* __restrict__ ob, float* __restrict__ logits) {
  int k = blockIdx.x * 4 + (threadIdx.x >> 6);
  int lane = threadIdx.x & 63;
  if (k >= KSEL) return;
  float a = 0.f;
  for (int j = lane; j < HIDD; j += 64) {
    float v = h1[k * HIDD + j];
    a += fmaxf(v, 0.f) * ow[j];
  }
  for (int off = 32; off; off >>= 1) a += __shfl_down(a, off, 64);
  if (lane == 0) logits[k] = a + ob[0];
}

__global__ __launch_bounds__(512) void softmax_kernel(const float* __restrict__ logits,
    float* __restrict__ out) {
  int t = threadIdx.x;
  float v = logits[t];
  __shared__ float red[512];
  red[t] = v;
  __syncthreads();
  for (int s = 256; s; s >>= 1) { if (t < s) red[t] = fmaxf(red[t], red[t + s]); __syncthreads(); }
  float mx = red[0];
  __syncthreads();
  float e = expf(v - mx);
  red[t] = e;
  __syncthreads();
  for (int s = 256; s; s >>= 1) { if (t < s) red[t] += red[t + s]; __syncthreads(); }
  out[t] = e / red[0];
}

// ---------------- launch ----------------

extern "C" void kernel_launch(void* const* d_in, const int* in_sizes, int n_in,
                              void* d_out, int out_size, void* d_ws, size_t ws_size,
                              hipStream_t stream) {
  const int* node_types = (const int*)d_in[0];
  const int* edge_index = (const int*)d_in[1];
  const int* indices = (const int*)d_in[2];
  const float* emb = (const float*)d_in[3];
  const float* conv0_w = (const float*)d_in[4];
  const float* bn_g = (const float*)d_in[5];
  const float* bn_b = (const float*)d_in[6];
  const float* res_w = (const float*)d_in[7];
  const float* hw = (const float*)d_in[8];
  const float* hb = (const float*)d_in[9];
  const float* ow = (const float*)d_in[10];
  const float* ob = (const float*)d_in[11];
  float* out = (float*)d_out;
  const int* src = edge_index;
  const int* dst = edge_index + NE;

  char* p = (char*)d_ws;
  size_t off = 0;
  auto alloc = [&](size_t bytes) -> void* {
    void* q = p + off;
    off += (bytes + 255) & ~(size_t)255;
    return q;
  };
  int* cnt = (int*)alloc(2 * NN * sizeof(int));        // cnt_in | cnt_out
  int* rp = (int*)alloc(2 * (NN + 1) * sizeof(int));   // rp_in | rp_out
  int* cur = (int*)alloc(2 * NN * sizeof(int));
  int* col_in = (int*)alloc((size_t)NE * sizeof(int));
  int* col_out = (int*)alloc((size_t)NE * sizeof(int));
  float* X = (float*)alloc((size_t)NN * CC * 4);
  float* H = (float*)alloc((size_t)NN * CC * 4);
  float* Y = (float*)alloc((size_t)NN * CC * 4);
  float* statsA = (float*)alloc(128 * 4);
  float* statsB = (float*)alloc(128 * 4);
  float* sel = (float*)alloc((size_t)KSEL * FULLW * 4);
  float* h1 = (float*)alloc((size_t)KSEL * HIDD * 4);
  float* logits = (float*)alloc(KSEL * 4);
  (void)ws_size; (void)in_sizes; (void)n_in; (void)out_size;

  int* cnt_in = cnt;  int* cnt_out = cnt + NN;
  int* rp_in = rp;    int* rp_out = rp + NN + 1;
  int* cur_in = cur;  int* cur_out = cur + NN;

  hipMemsetAsync(cnt, 0, 2 * NN * sizeof(int), stream);
  hipLaunchKernelGGL(hist_kernel, dim3(1024), dim3(256), 0, stream, src, dst, cnt_in, cnt_out);
  hipLaunchKernelGGL(scan_kernel, dim3(2), dim3(1024), 0, stream, cnt, rp);
  hipLaunchKernelGGL(initcur_kernel, dim3((2 * NN + 255) / 256), dim3(256), 0, stream,
                     rp_in, rp_out, cur_in, cur_out, statsA);
  hipLaunchKernelGGL(fill_kernel, dim3(1024), dim3(256), 0, stream, src, dst,
                     cur_in, cur_out, col_in, col_out);

  hipLaunchKernelGGL(embed_kernel, dim3((NN * CC + 255) / 256), dim3(256), 0, stream,
                     node_types, emb, X);
  hipLaunchKernelGGL(gather_sel_kernel, dim3(KSEL * CC / 256), dim3(256), 0, stream,
                     X, indices, sel, 0);

  // conv0 (no BN); accumulate relu stats of its output into statsA
  hipLaunchKernelGGL(mm_kernel, dim3(782), dim3(256), 0, stream, X, Y, conv0_w,
                     (const float*)nullptr, (const float*)nullptr, (const float*)nullptr,
                     (float*)nullptr);
  hipLaunchKernelGGL(seg_kernel, dim3(1024), dim3(256), 0, stream, Y, (const float*)nullptr, X,
                     rp_in, col_in, rp_out, col_out, statsA);
  hipLaunchKernelGGL(gather_sel_kernel, dim3(KSEL * CC / 256), dim3(256), 0, stream,
                     X, indices, sel, CC);

  for (int l = 0; l < LL; ++l) {
    const float* w1 = res_w + (size_t)(l * 2 + 0) * 4096;
    const float* w2 = res_w + (size_t)(l * 2 + 1) * 4096;
    const float* g1 = bn_g + (l * 2 + 0) * CC;
    const float* b1 = bn_b + (l * 2 + 0) * CC;
    const float* g2 = bn_g + (l * 2 + 1) * CC;
    const float* b2 = bn_b + (l * 2 + 1) * CC;
    hipLaunchKernelGGL(mm_kernel, dim3(782), dim3(256), 0, stream, X, Y, w1, statsA, g1, b1, statsB);
    hipLaunchKernelGGL(seg_kernel, dim3(1024), dim3(256), 0, stream, Y, (const float*)nullptr, H,
                       rp_in, col_in, rp_out, col_out, statsB);
    hipLaunchKernelGGL(mm_kernel, dim3(782), dim3(256), 0, stream, H, Y, w2, statsB, g2, b2, statsA);
    hipLaunchKernelGGL(seg_kernel, dim3(1024), dim3(256), 0, stream, Y, X, X,
                       rp_in, col_in, rp_out, col_out, statsA);
    hipLaunchKernelGGL(gather_sel_kernel, dim3(KSEL * CC / 256), dim3(256), 0, stream,
                       X, indices, sel, 2 * CC + l * CC);
  }

  hipLaunchKernelGGL(hidden_kernel, dim3(1024), dim3(64), 0, stream, sel, hw, hb, h1);
  hipLaunchKernelGGL(out_kernel, dim3(KSEL / 4), dim3(256), 0, stream, h1, ow, ob, logits);
  hipLaunchKernelGGL(softmax_kernel, dim3(1), dim3(512), 0, stream, logits, out);
}

// Round 2
// 4298.058 us; speedup vs baseline: 1.2059x; 1.2059x over previous
//
#include <hip/hip_runtime.h>

#define NN 50000
#define NE 1000000
#define CC 64
#define LL 16
#define KSEL 512
#define HIDD 1024
#define FULLW 1152
#define EPSV 1e-5f

// ---------------- CSR build ----------------

__global__ __launch_bounds__(256) void hist_kernel(const int* __restrict__ src,
    const int* __restrict__ dst, int* __restrict__ cnt_in, int* __restrict__ cnt_out) {
  int stride = gridDim.x * blockDim.x;
  for (int e = blockIdx.x * blockDim.x + threadIdx.x; e < NE; e += stride) {
    atomicAdd(&cnt_in[dst[e]], 1);
    atomicAdd(&cnt_out[src[e]], 1);
  }
}

__global__ __launch_bounds__(1024) void scan_kernel(const int* __restrict__ cnt,
    int* __restrict__ rp) {
  // blockIdx.x = 0: in, 1: out
  const int* c = cnt + blockIdx.x * NN;
  int* r = rp + blockIdx.x * (NN + 1);
  __shared__ int part[1024];
  int t = threadIdx.x;
  const int CH = (NN + 1023) / 1024;
  int beg = t * CH;
  int end = min(beg + CH, NN);
  int s = 0;
  for (int i = beg; i < end; ++i) s += c[i];
  part[t] = s;
  __syncthreads();
  if (t == 0) {
    int run = 0;
    for (int i = 0; i < 1024; ++i) { int v = part[i]; part[i] = run; run += v; }
  }
  __syncthreads();
  int off = part[t];
  for (int i = beg; i < end; ++i) { r[i] = off; off += c[i]; }
  if (t == 1023) r[NN] = off;
}

__global__ __launch_bounds__(256) void initcur_kernel(const int* __restrict__ rp_in,
    const int* __restrict__ rp_out, int* __restrict__ cur_in, int* __restrict__ cur_out,
    float* __restrict__ statsA) {
  int i = blockIdx.x * 256 + threadIdx.x;
  if (i < NN) cur_in[i] = rp_in[i];
  else if (i < 2 * NN) cur_out[i - NN] = rp_out[i - NN];
  if (blockIdx.x == 0 && threadIdx.x < 128) statsA[threadIdx.x] = 0.f;
}

__global__ __launch_bounds__(256) void fill_kernel(const int* __restrict__ src,
    const int* __restrict__ dst, int* __restrict__ cur_in, int* __restrict__ cur_out,
    int* __restrict__ col_in, int* __restrict__ col_out) {
  int stride = gridDim.x * blockDim.x;
  for (int e = blockIdx.x * blockDim.x + threadIdx.x; e < NE; e += stride) {
    int s = src[e], d = dst[e];
    int p = atomicAdd(&cur_in[d], 1);
    col_in[p] = s;
    int q = atomicAdd(&cur_out[s], 1);
    col_out[q] = d;
  }
}

// ---------------- embedding + sel gather ----------------

__global__ __launch_bounds__(256) void embed_kernel(const int* __restrict__ nt,
    const float* __restrict__ emb, float* __restrict__ X) {
  int id = blockIdx.x * 256 + threadIdx.x;
  if (id >= NN * CC) return;
  X[id] = emb[nt[id >> 6] * CC + (id & 63)];
}

__global__ __launch_bounds__(256) void gather_sel_kernel(const float* __restrict__ xsrc,
    const int* __restrict__ idx, float* __restrict__ sel, int coloff) {
  int tid = blockIdx.x * 256 + threadIdx.x;
  if (tid >= KSEL * CC) return;
  int k = tid >> 6, cch = tid & 63;
  sel[k * FULLW + coloff + cch] = xsrc[idx[k] * CC + cch];
}

// ---------------- matmul: Y = f(X) @ W ----------------
// W layout [2][64][32]; output col j -> W[j>>5][c][j&31].
// f = BN(relu(.)) from stats (sum,sumsq) if stats!=null else identity.
// Block 0 zeroes stats_zero (the OTHER stats buffer) for the next producer.

__global__ __launch_bounds__(256) void mm_kernel(const float* __restrict__ X,
    float* __restrict__ Y, const float* __restrict__ W,
    const float* __restrict__ stats, const float* __restrict__ gamma,
    const float* __restrict__ beta, float* __restrict__ stats_zero) {
  int t = threadIdx.x;
  int lane = t & 63;
  int wid = t >> 6;
  float wreg[CC];
  {
    const float* wb = W + (lane >> 5) * 2048 + (lane & 31);
#pragma unroll
    for (int c2 = 0; c2 < CC; ++c2) wreg[c2] = wb[c2 * 32];
  }
  __shared__ float sc[CC], sh[CC];
  __shared__ __align__(16) float Xs[64][CC];
  if (t < CC) {
    float scale = 1.f, shift = 0.f;
    if (stats) {
      float m = stats[t] * (1.f / NN);
      float v = stats[CC + t] * (1.f / NN) - m * m;
      float is = rsqrtf(v + EPSV);
      scale = gamma[t] * is;
      shift = beta[t] - m * scale;
    }
    sc[t] = scale; sh[t] = shift;
  }
  if (stats_zero && blockIdx.x == 0 && t < 128) stats_zero[t] = 0.f;
  const bool bn = (stats != nullptr);
  for (int row0 = blockIdx.x * 64; row0 < NN; row0 += gridDim.x * 64) {
    int nrows = min(64, NN - row0);
    __syncthreads();
    for (int idx = t; idx < nrows * CC; idx += 256) {
      int r = idx >> 6, cch = idx & 63;
      float v = X[(row0 + r) * CC + cch];
      if (bn) { v = fmaxf(v, 0.f); v = v * sc[cch] + sh[cch]; }
      Xs[r][cch] = v;
    }
    __syncthreads();
    for (int r = wid; r < nrows; r += 4) {
      const float* xr = &Xs[r][0];
      float a0 = 0.f, a1 = 0.f, a2 = 0.f, a3 = 0.f;
#pragma unroll
      for (int c2 = 0; c2 < CC; c2 += 4) {
        float4 xv = *(const float4*)(xr + c2);
        a0 += xv.x * wreg[c2];
        a1 += xv.y * wreg[c2 + 1];
        a2 += xv.z * wreg[c2 + 2];
        a3 += xv.w * wreg[c2 + 3];
      }
      Y[(row0 + r) * CC + lane] = (a0 + a1) + (a2 + a3);
    }
  }
}

// ---------------- segment-sum (both directions) + optional skip + BN stats ----------------
// channels 0..31: sum over in-edges of Y[src][c]; 32..63: out-edges of Y[dst][c].
// 4 independent accumulator chains -> 4 outstanding 128B gathers per wave (MLP).

__global__ __launch_bounds__(256) void seg_kernel(
    const float* __restrict__ Y, const float* skip, float* OUT,
    const int* __restrict__ rp_in, const int* __restrict__ col_in,
    const int* __restrict__ rp_out, const int* __restrict__ col_out,
    float* __restrict__ stats_acc) {
  int t = threadIdx.x;
  int c = t & 63;
  int local = t >> 6;
  const int* rp = (c < 32) ? rp_in : rp_out;
  const int* col = (c < 32) ? col_in : col_out;
  float s1 = 0.f, s2 = 0.f;
  for (int i0 = blockIdx.x * 4; i0 < NN; i0 += gridDim.x * 4) {
    int i = i0 + local;
    if (i < NN) {
      int beg = rp[i], end = rp[i + 1];
      float a0 = 0.f, a1 = 0.f, a2 = 0.f, a3 = 0.f;
      int e = beg;
      for (; e + 4 <= end; e += 4) {
        int j0 = col[e], j1 = col[e + 1], j2 = col[e + 2], j3 = col[e + 3];
        a0 += Y[j0 * CC + c];
        a1 += Y[j1 * CC + c];
        a2 += Y[j2 * CC + c];
        a3 += Y[j3 * CC + c];
      }
      if (e + 2 <= end) {
        int j0 = col[e], j1 = col[e + 1];
        a0 += Y[j0 * CC + c];
        a1 += Y[j1 * CC + c];
        e += 2;
      }
      if (e < end) a2 += Y[col[e] * CC + c];
      float acc = (a0 + a1) + (a2 + a3);
      if (skip) acc += skip[i * CC + c];
      OUT[i * CC + c] = acc;
      float r = fmaxf(acc, 0.f);
      s1 += r; s2 += r * r;
    }
  }
  if (stats_acc) {
    __shared__ float red1[256], red2[256];
    red1[t] = s1; red2[t] = s2;
    __syncthreads();
    if (t < 64) {
      float v1 = red1[t] + red1[t + 64] + red1[t + 128] + red1[t + 192];
      float v2 = red2[t] + red2[t + 64] + red2[t + 128] + red2[t + 192];
      atomicAdd(&stats_acc[t], v1);
      atomicAdd(&stats_acc[CC + t], v2);
    }
  }
}

// ---------------- head ----------------

__global__ __launch_bounds__(64) void hidden_kernel(const float* __restrict__ sel,
    const float* __restrict__ Wh, const float* __restrict__ bh, float* __restrict__ h1) {
  int lane = threadIdx.x;
  int rb = blockIdx.x & 63;   // 64 row-blocks of 8 rows
  int jb = blockIdx.x >> 6;   // 16 col-blocks of 64 cols
  int j = jb * 64 + lane;
  int r0 = rb * 8;
  float acc[8];
#pragma unroll
  for (int r = 0; r < 8; ++r) acc[r] = 0.f;
  __shared__ __align__(16) float Ss[8][64];
  for (int k0 = 0; k0 < FULLW; k0 += 64) {
    float wreg[64];
#pragma unroll
    for (int c2 = 0; c2 < 64; ++c2) wreg[c2] = Wh[(k0 + c2) * HIDD + j];
    __syncthreads();
#pragma unroll
    for (int r = 0; r < 8; ++r) {
      float v = sel[(r0 + r) * FULLW + k0 + lane];
      Ss[r][lane] = fmaxf(v, 0.f);
    }
    __syncthreads();
#pragma unroll
    for (int r = 0; r < 8; ++r) {
      const float* sr = &Ss[r][0];
      float a0 = 0.f, a1 = 0.f, a2 = 0.f, a3 = 0.f;
#pragma unroll
      for (int c2 = 0; c2 < 64; c2 += 4) {
        float4 sv = *(const float4*)(sr + c2);
        a0 += sv.x * wreg[c2]; a1 += sv.y * wreg[c2 + 1];
        a2 += sv.z * wreg[c2 + 2]; a3 += sv.w * wreg[c2 + 3];
      }
      acc[r] += (a0 + a1) + (a2 + a3);
    }
  }
#pragma unroll
  for (int r = 0; r < 8; ++r) h1[(r0 + r) * HIDD + j] = acc[r] + bh[j];
}

__global__ __launch_bounds__(256) void out_kernel(const float* __restrict__ h1,
    const float* __restrict__ ow, const float* __restrict__ ob, float* __restrict__ logits) {
  int k = blockIdx.x * 4 + (threadIdx.x >> 6);
  int lane = threadIdx.x & 63;
  if (k >= KSEL) return;
  float a = 0.f;
  for (int j = lane; j < HIDD; j += 64) {
    float v = h1[k * HIDD + j];
    a += fmaxf(v, 0.f) * ow[j];
  }
  for (int off = 32; off; off >>= 1) a += __shfl_down(a, off, 64);
  if (lane == 0) logits[k] = a + ob[0];
}

__global__ __launch_bounds__(512) void softmax_kernel(const float* __restrict__ logits,
    float* __restrict__ out) {
  int t = threadIdx.x;
  float v = logits[t];
  __shared__ float red[512];
  red[t] = v;
  __syncthreads();
  for (int s = 256; s; s >>= 1) { if (t < s) red[t] = fmaxf(red[t], red[t + s]); __syncthreads(); }
  float mx = red[0];
  __syncthreads();
  float e = expf(v - mx);
  red[t] = e;
  __syncthreads();
  for (int s = 256; s; s >>= 1) { if (t < s) red[t] += red[t + s]; __syncthreads(); }
  out[t] = e / red[0];
}

// ---------------- launch ----------------

extern "C" void kernel_launch(void* const* d_in, const int* in_sizes, int n_in,
                              void* d_out, int out_size, void* d_ws, size_t ws_size,
                              hipStream_t stream) {
  const int* node_types = (const int*)d_in[0];
  const int* edge_index = (const int*)d_in[1];
  const int* indices = (const int*)d_in[2];
  const float* emb = (const float*)d_in[3];
  const float* conv0_w = (const float*)d_in[4];
  const float* bn_g = (const float*)d_in[5];
  const float* bn_b = (const float*)d_in[6];
  const float* res_w = (const float*)d_in[7];
  const float* hw = (const float*)d_in[8];
  const float* hb = (const float*)d_in[9];
  const float* ow = (const float*)d_in[10];
  const float* ob = (const float*)d_in[11];
  float* out = (float*)d_out;
  const int* src = edge_index;
  const int* dst = edge_index + NE;

  char* p = (char*)d_ws;
  size_t off = 0;
  auto alloc = [&](size_t bytes) -> void* {
    void* q = p + off;
    off += (bytes + 255) & ~(size_t)255;
    return q;
  };
  int* cnt = (int*)alloc(2 * NN * sizeof(int));        // cnt_in | cnt_out
  int* rp = (int*)alloc(2 * (NN + 1) * sizeof(int));   // rp_in | rp_out
  int* cur = (int*)alloc(2 * NN * sizeof(int));
  int* col_in = (int*)alloc((size_t)NE * sizeof(int));
  int* col_out = (int*)alloc((size_t)NE * sizeof(int));
  float* X = (float*)alloc((size_t)NN * CC * 4);
  float* H = (float*)alloc((size_t)NN * CC * 4);
  float* Y = (float*)alloc((size_t)NN * CC * 4);
  float* statsA = (float*)alloc(128 * 4);
  float* statsB = (float*)alloc(128 * 4);
  float* sel = (float*)alloc((size_t)KSEL * FULLW * 4);
  float* h1 = (float*)alloc((size_t)KSEL * HIDD * 4);
  float* logits = (float*)alloc(KSEL * 4);
  (void)ws_size; (void)in_sizes; (void)n_in; (void)out_size;

  int* cnt_in = cnt;  int* cnt_out = cnt + NN;
  int* rp_in = rp;    int* rp_out = rp + NN + 1;
  int* cur_in = cur;  int* cur_out = cur + NN;

  hipMemsetAsync(cnt, 0, 2 * NN * sizeof(int), stream);
  hipLaunchKernelGGL(hist_kernel, dim3(1024), dim3(256), 0, stream, src, dst, cnt_in, cnt_out);
  hipLaunchKernelGGL(scan_kernel, dim3(2), dim3(1024), 0, stream, cnt, rp);
  hipLaunchKernelGGL(initcur_kernel, dim3((2 * NN + 255) / 256), dim3(256), 0, stream,
                     rp_in, rp_out, cur_in, cur_out, statsA);
  hipLaunchKernelGGL(fill_kernel, dim3(1024), dim3(256), 0, stream, src, dst,
                     cur_in, cur_out, col_in, col_out);

  hipLaunchKernelGGL(embed_kernel, dim3((NN * CC + 255) / 256), dim3(256), 0, stream,
                     node_types, emb, X);
  hipLaunchKernelGGL(gather_sel_kernel, dim3(KSEL * CC / 256), dim3(256), 0, stream,
                     X, indices, sel, 0);

  // conv0 (no BN); accumulate relu stats of its output into statsA
  hipLaunchKernelGGL(mm_kernel, dim3(782), dim3(256), 0, stream, X, Y, conv0_w,
                     (const float*)nullptr, (const float*)nullptr, (const float*)nullptr,
                     (float*)nullptr);
  hipLaunchKernelGGL(seg_kernel, dim3(2048), dim3(256), 0, stream, Y, (const float*)nullptr, X,
                     rp_in, col_in, rp_out, col_out, statsA);
  hipLaunchKernelGGL(gather_sel_kernel, dim3(KSEL * CC / 256), dim3(256), 0, stream,
                     X, indices, sel, CC);

  for (int l = 0; l < LL; ++l) {
    const float* w1 = res_w + (size_t)(l * 2 + 0) * 4096;
    const float* w2 = res_w + (size_t)(l * 2 + 1) * 4096;
    const float* g1 = bn_g + (l * 2 + 0) * CC;
    const float* b1 = bn_b + (l * 2 + 0) * CC;
    const float* g2 = bn_g + (l * 2 + 1) * CC;
    const float* b2 = bn_b + (l * 2 + 1) * CC;
    hipLaunchKernelGGL(mm_kernel, dim3(782), dim3(256), 0, stream, X, Y, w1, statsA, g1, b1, statsB);
    hipLaunchKernelGGL(seg_kernel, dim3(2048), dim3(256), 0, stream, Y, (const float*)nullptr, H,
                       rp_in, col_in, rp_out, col_out, statsB);
    hipLaunchKernelGGL(mm_kernel, dim3(782), dim3(256), 0, stream, H, Y, w2, statsB, g2, b2, statsA);
    hipLaunchKernelGGL(seg_kernel, dim3(2048), dim3(256), 0, stream, Y, X, X,
                       rp_in, col_in, rp_out, col_out, statsA);
    hipLaunchKernelGGL(gather_sel_kernel, dim3(KSEL * CC / 256), dim3(256), 0, stream,
                       X, indices, sel, 2 * CC + l * CC);
  }

  hipLaunchKernelGGL(hidden_kernel, dim3(1024), dim3(64), 0, stream, sel, hw, hb, h1);
  hipLaunchKernelGGL(out_kernel, dim3(KSEL / 4), dim3(256), 0, stream, h1, ow, ob, logits);
  hipLaunchKernelGGL(softmax_kernel, dim3(1), dim3(512), 0, stream, logits, out);
}

// Round 3
// 4034.593 us; speedup vs baseline: 1.2846x; 1.0653x over previous
//
#include <hip/hip_runtime.h>
#include <hip/hip_bf16.h>

#define NN 50000
#define NE 1000000
#define CC 64
#define LL 16
#define KSEL 512
#define HIDD 1024
#define FULLW 1152
#define EPSV 1e-5f

// ---------------- CSR build ----------------

__global__ __launch_bounds__(256) void hist_kernel(const int* __restrict__ src,
    const int* __restrict__ dst, int* __restrict__ cnt_in, int* __restrict__ cnt_out) {
  int stride = gridDim.x * blockDim.x;
  for (int e = blockIdx.x * blockDim.x + threadIdx.x; e < NE; e += stride) {
    atomicAdd(&cnt_in[dst[e]], 1);
    atomicAdd(&cnt_out[src[e]], 1);
  }
}

__global__ __launch_bounds__(1024) void scan_kernel(const int* __restrict__ cnt,
    int* __restrict__ rp) {
  // blockIdx.x = 0: in, 1: out
  const int* c = cnt + blockIdx.x * NN;
  int* r = rp + blockIdx.x * (NN + 1);
  __shared__ int part[1024];
  int t = threadIdx.x;
  const int CH = (NN + 1023) / 1024;
  int beg = t * CH;
  int end = min(beg + CH, NN);
  int s = 0;
  for (int i = beg; i < end; ++i) s += c[i];
  part[t] = s;
  __syncthreads();
  if (t == 0) {
    int run = 0;
    for (int i = 0; i < 1024; ++i) { int v = part[i]; part[i] = run; run += v; }
  }
  __syncthreads();
  int off = part[t];
  for (int i = beg; i < end; ++i) { r[i] = off; off += c[i]; }
  if (t == 1023) r[NN] = off;
}

__global__ __launch_bounds__(256) void initcur_kernel(const int* __restrict__ rp_in,
    const int* __restrict__ rp_out, int* __restrict__ cur_in, int* __restrict__ cur_out,
    float* __restrict__ statsA) {
  int i = blockIdx.x * 256 + threadIdx.x;
  if (i < NN) cur_in[i] = rp_in[i];
  else if (i < 2 * NN) cur_out[i - NN] = rp_out[i - NN];
  if (blockIdx.x == 0 && threadIdx.x < 128) statsA[threadIdx.x] = 0.f;
}

__global__ __launch_bounds__(256) void fill_kernel(const int* __restrict__ src,
    const int* __restrict__ dst, int* __restrict__ cur_in, int* __restrict__ cur_out,
    int* __restrict__ col_in, int* __restrict__ col_out) {
  int stride = gridDim.x * blockDim.x;
  for (int e = blockIdx.x * blockDim.x + threadIdx.x; e < NE; e += stride) {
    int s = src[e], d = dst[e];
    int p = atomicAdd(&cur_in[d], 1);
    col_in[p] = s;
    int q = atomicAdd(&cur_out[s], 1);
    col_out[q] = d;
  }
}

// ---------------- embedding + sel gather ----------------

__global__ __launch_bounds__(256) void embed_kernel(const int* __restrict__ nt,
    const float* __restrict__ emb, float* __restrict__ X) {
  int id = blockIdx.x * 256 + threadIdx.x;
  if (id >= NN * CC) return;
  X[id] = emb[nt[id >> 6] * CC + (id & 63)];
}

__global__ __launch_bounds__(256) void gather_sel_kernel(const float* __restrict__ xsrc,
    const int* __restrict__ idx, float* __restrict__ sel, int coloff) {
  int tid = blockIdx.x * 256 + threadIdx.x;
  if (tid >= KSEL * CC) return;
  int k = tid >> 6, cch = tid & 63;
  sel[k * FULLW + coloff + cch] = xsrc[idx[k] * CC + cch];
}

// ---------------- matmul: Y(bf16) = f(X) @ W ----------------
// W layout [2][64][32]; output col j -> W[j>>5][c][j&31].
// f = BN(relu(.)) from stats (sum,sumsq) if stats!=null else identity.
// Block 0 zeroes stats_zero (the OTHER stats buffer) for the next producer.

__global__ __launch_bounds__(256) void mm_kernel(const float* __restrict__ X,
    __hip_bfloat16* __restrict__ Y, const float* __restrict__ W,
    const float* __restrict__ stats, const float* __restrict__ gamma,
    const float* __restrict__ beta, float* __restrict__ stats_zero) {
  int t = threadIdx.x;
  int lane = t & 63;
  int wid = t >> 6;
  float wreg[CC];
  {
    const float* wb = W + (lane >> 5) * 2048 + (lane & 31);
#pragma unroll
    for (int c2 = 0; c2 < CC; ++c2) wreg[c2] = wb[c2 * 32];
  }
  __shared__ float sc[CC], sh[CC];
  __shared__ __align__(16) float Xs[64][CC];
  if (t < CC) {
    float scale = 1.f, shift = 0.f;
    if (stats) {
      float m = stats[t] * (1.f / NN);
      float v = stats[CC + t] * (1.f / NN) - m * m;
      float is = rsqrtf(v + EPSV);
      scale = gamma[t] * is;
      shift = beta[t] - m * scale;
    }
    sc[t] = scale; sh[t] = shift;
  }
  if (stats_zero && blockIdx.x == 0 && t < 128) stats_zero[t] = 0.f;
  const bool bn = (stats != nullptr);
  for (int row0 = blockIdx.x * 64; row0 < NN; row0 += gridDim.x * 64) {
    int nrows = min(64, NN - row0);
    __syncthreads();
    for (int idx = t; idx < nrows * CC; idx += 256) {
      int r = idx >> 6, cch = idx & 63;
      float v = X[(row0 + r) * CC + cch];
      if (bn) { v = fmaxf(v, 0.f); v = v * sc[cch] + sh[cch]; }
      Xs[r][cch] = v;
    }
    __syncthreads();
    for (int r = wid; r < nrows; r += 4) {
      const float* xr = &Xs[r][0];
      float a0 = 0.f, a1 = 0.f, a2 = 0.f, a3 = 0.f;
#pragma unroll
      for (int c2 = 0; c2 < CC; c2 += 4) {
        float4 xv = *(const float4*)(xr + c2);
        a0 += xv.x * wreg[c2];
        a1 += xv.y * wreg[c2 + 1];
        a2 += xv.z * wreg[c2 + 2];
        a3 += xv.w * wreg[c2 + 3];
      }
      Y[(row0 + r) * CC + lane] = __float2bfloat16((a0 + a1) + (a2 + a3));
    }
  }
}

// ---------------- segment-sum (both directions) + optional skip + BN stats ----------------
// channels 0..31: sum over in-edges of Y[src][c]; 32..63: out-edges of Y[dst][c].
// Y is bf16 (64B per half-row gather); 8 independent accumulator chains for MLP.

__global__ __launch_bounds__(256) void seg_kernel(
    const __hip_bfloat16* __restrict__ Y, const float* skip, float* OUT,
    const int* __restrict__ rp_in, const int* __restrict__ col_in,
    const int* __restrict__ rp_out, const int* __restrict__ col_out,
    float* __restrict__ stats_acc) {
  int t = threadIdx.x;
  int c = t & 63;
  int local = t >> 6;
  const int* rp = (c < 32) ? rp_in : rp_out;
  const int* col = (c < 32) ? col_in : col_out;
  float s1 = 0.f, s2 = 0.f;
  for (int i0 = blockIdx.x * 4; i0 < NN; i0 += gridDim.x * 4) {
    int i = i0 + local;
    if (i < NN) {
      int beg = rp[i], end = rp[i + 1];
      float a0 = 0.f, a1 = 0.f, a2 = 0.f, a3 = 0.f;
      float a4 = 0.f, a5 = 0.f, a6 = 0.f, a7 = 0.f;
      int e = beg;
      for (; e + 8 <= end; e += 8) {
        int j0 = col[e], j1 = col[e + 1], j2 = col[e + 2], j3 = col[e + 3];
        int j4 = col[e + 4], j5 = col[e + 5], j6 = col[e + 6], j7 = col[e + 7];
        a0 += __bfloat162float(Y[j0 * CC + c]);
        a1 += __bfloat162float(Y[j1 * CC + c]);
        a2 += __bfloat162float(Y[j2 * CC + c]);
        a3 += __bfloat162float(Y[j3 * CC + c]);
        a4 += __bfloat162float(Y[j4 * CC + c]);
        a5 += __bfloat162float(Y[j5 * CC + c]);
        a6 += __bfloat162float(Y[j6 * CC + c]);
        a7 += __bfloat162float(Y[j7 * CC + c]);
      }
      if (e + 4 <= end) {
        int j0 = col[e], j1 = col[e + 1], j2 = col[e + 2], j3 = col[e + 3];
        a0 += __bfloat162float(Y[j0 * CC + c]);
        a1 += __bfloat162float(Y[j1 * CC + c]);
        a2 += __bfloat162float(Y[j2 * CC + c]);
        a3 += __bfloat162float(Y[j3 * CC + c]);
        e += 4;
      }
      if (e + 2 <= end) {
        int j0 = col[e], j1 = col[e + 1];
        a4 += __bfloat162float(Y[j0 * CC + c]);
        a5 += __bfloat162float(Y[j1 * CC + c]);
        e += 2;
      }
      if (e < end) a6 += __bfloat162float(Y[col[e] * CC + c]);
      float acc = ((a0 + a1) + (a2 + a3)) + ((a4 + a5) + (a6 + a7));
      if (skip) acc += skip[i * CC + c];
      OUT[i * CC + c] = acc;
      float r = fmaxf(acc, 0.f);
      s1 += r; s2 += r * r;
    }
  }
  if (stats_acc) {
    __shared__ float red1[256], red2[256];
    red1[t] = s1; red2[t] = s2;
    __syncthreads();
    if (t < 64) {
      float v1 = red1[t] + red1[t + 64] + red1[t + 128] + red1[t + 192];
      float v2 = red2[t] + red2[t + 64] + red2[t + 128] + red2[t + 192];
      atomicAdd(&stats_acc[t], v1);
      atomicAdd(&stats_acc[CC + t], v2);
    }
  }
}

// ---------------- head ----------------

__global__ __launch_bounds__(64) void hidden_kernel(const float* __restrict__ sel,
    const float* __restrict__ Wh, const float* __restrict__ bh, float* __restrict__ h1) {
  int lane = threadIdx.x;
  int rb = blockIdx.x & 63;   // 64 row-blocks of 8 rows
  int jb = blockIdx.x >> 6;   // 16 col-blocks of 64 cols
  int j = jb * 64 + lane;
  int r0 = rb * 8;
  float acc[8];
#pragma unroll
  for (int r = 0; r < 8; ++r) acc[r] = 0.f;
  __shared__ __align__(16) float Ss[8][64];
  for (int k0 = 0; k0 < FULLW; k0 += 64) {
    float wreg[64];
#pragma unroll
    for (int c2 = 0; c2 < 64; ++c2) wreg[c2] = Wh[(k0 + c2) * HIDD + j];
    __syncthreads();
#pragma unroll
    for (int r = 0; r < 8; ++r) {
      float v = sel[(r0 + r) * FULLW + k0 + lane];
      Ss[r][lane] = fmaxf(v, 0.f);
    }
    __syncthreads();
#pragma unroll
    for (int r = 0; r < 8; ++r) {
      const float* sr = &Ss[r][0];
      float a0 = 0.f, a1 = 0.f, a2 = 0.f, a3 = 0.f;
#pragma unroll
      for (int c2 = 0; c2 < 64; c2 += 4) {
        float4 sv = *(const float4*)(sr + c2);
        a0 += sv.x * wreg[c2]; a1 += sv.y * wreg[c2 + 1];
        a2 += sv.z * wreg[c2 + 2]; a3 += sv.w * wreg[c2 + 3];
      }
      acc[r] += (a0 + a1) + (a2 + a3);
    }
  }
#pragma unroll
  for (int r = 0; r < 8; ++r) h1[(r0 + r) * HIDD + j] = acc[r] + bh[j];
}

__global__ __launch_bounds__(256) void out_kernel(const float* __restrict__ h1,
    const float* __restrict__ ow, const float* __restrict__ ob, float* __restrict__ logits) {
  int k = blockIdx.x * 4 + (threadIdx.x >> 6);
  int lane = threadIdx.x & 63;
  if (k >= KSEL) return;
  float a = 0.f;
  for (int j = lane; j < HIDD; j += 64) {
    float v = h1[k * HIDD + j];
    a += fmaxf(v, 0.f) * ow[j];
  }
  for (int off = 32; off; off >>= 1) a += __shfl_down(a, off, 64);
  if (lane == 0) logits[k] = a + ob[0];
}

__global__ __launch_bounds__(512) void softmax_kernel(const float* __restrict__ logits,
    float* __restrict__ out) {
  int t = threadIdx.x;
  float v = logits[t];
  __shared__ float red[512];
  red[t] = v;
  __syncthreads();
  for (int s = 256; s; s >>= 1) { if (t < s) red[t] = fmaxf(red[t], red[t + s]); __syncthreads(); }
  float mx = red[0];
  __syncthreads();
  float e = expf(v - mx);
  red[t] = e;
  __syncthreads();
  for (int s = 256; s; s >>= 1) { if (t < s) red[t] += red[t + s]; __syncthreads(); }
  out[t] = e / red[0];
}

// ---------------- launch ----------------

extern "C" void kernel_launch(void* const* d_in, const int* in_sizes, int n_in,
                              void* d_out, int out_size, void* d_ws, size_t ws_size,
                              hipStream_t stream) {
  const int* node_types = (const int*)d_in[0];
  const int* edge_index = (const int*)d_in[1];
  const int* indices = (const int*)d_in[2];
  const float* emb = (const float*)d_in[3];
  const float* conv0_w = (const float*)d_in[4];
  const float* bn_g = (const float*)d_in[5];
  const float* bn_b = (const float*)d_in[6];
  const float* res_w = (const float*)d_in[7];
  const float* hw = (const float*)d_in[8];
  const float* hb = (const float*)d_in[9];
  const float* ow = (const float*)d_in[10];
  const float* ob = (const float*)d_in[11];
  float* out = (float*)d_out;
  const int* src = edge_index;
  const int* dst = edge_index + NE;

  char* p = (char*)d_ws;
  size_t off = 0;
  auto alloc = [&](size_t bytes) -> void* {
    void* q = p + off;
    off += (bytes + 255) & ~(size_t)255;
    return q;
  };
  int* cnt = (int*)alloc(2 * NN * sizeof(int));        // cnt_in | cnt_out
  int* rp = (int*)alloc(2 * (NN + 1) * sizeof(int));   // rp_in | rp_out
  int* cur = (int*)alloc(2 * NN * sizeof(int));
  int* col_in = (int*)alloc((size_t)NE * sizeof(int));
  int* col_out = (int*)alloc((size_t)NE * sizeof(int));
  float* X = (float*)alloc((size_t)NN * CC * 4);
  float* H = (float*)alloc((size_t)NN * CC * 4);
  __hip_bfloat16* Y = (__hip_bfloat16*)alloc((size_t)NN * CC * 2);
  float* statsA = (float*)alloc(128 * 4);
  float* statsB = (float*)alloc(128 * 4);
  float* sel = (float*)alloc((size_t)KSEL * FULLW * 4);
  float* h1 = (float*)alloc((size_t)KSEL * HIDD * 4);
  float* logits = (float*)alloc(KSEL * 4);
  (void)ws_size; (void)in_sizes; (void)n_in; (void)out_size;

  int* cnt_in = cnt;  int* cnt_out = cnt + NN;
  int* rp_in = rp;    int* rp_out = rp + NN + 1;
  int* cur_in = cur;  int* cur_out = cur + NN;

  hipMemsetAsync(cnt, 0, 2 * NN * sizeof(int), stream);
  hipLaunchKernelGGL(hist_kernel, dim3(1024), dim3(256), 0, stream, src, dst, cnt_in, cnt_out);
  hipLaunchKernelGGL(scan_kernel, dim3(2), dim3(1024), 0, stream, cnt, rp);
  hipLaunchKernelGGL(initcur_kernel, dim3((2 * NN + 255) / 256), dim3(256), 0, stream,
                     rp_in, rp_out, cur_in, cur_out, statsA);
  hipLaunchKernelGGL(fill_kernel, dim3(1024), dim3(256), 0, stream, src, dst,
                     cur_in, cur_out, col_in, col_out);

  hipLaunchKernelGGL(embed_kernel, dim3((NN * CC + 255) / 256), dim3(256), 0, stream,
                     node_types, emb, X);
  hipLaunchKernelGGL(gather_sel_kernel, dim3(KSEL * CC / 256), dim3(256), 0, stream,
                     X, indices, sel, 0);

  // conv0 (no BN); accumulate relu stats of its output into statsA
  hipLaunchKernelGGL(mm_kernel, dim3(782), dim3(256), 0, stream, X, Y, conv0_w,
                     (const float*)nullptr, (const float*)nullptr, (const float*)nullptr,
                     (float*)nullptr);
  hipLaunchKernelGGL(seg_kernel, dim3(2048), dim3(256), 0, stream, Y, (const float*)nullptr, X,
                     rp_in, col_in, rp_out, col_out, statsA);
  hipLaunchKernelGGL(gather_sel_kernel, dim3(KSEL * CC / 256), dim3(256), 0, stream,
                     X, indices, sel, CC);

  for (int l = 0; l < LL; ++l) {
    const float* w1 = res_w + (size_t)(l * 2 + 0) * 4096;
    const float* w2 = res_w + (size_t)(l * 2 + 1) * 4096;
    const float* g1 = bn_g + (l * 2 + 0) * CC;
    const float* b1 = bn_b + (l * 2 + 0) * CC;
    const float* g2 = bn_g + (l * 2 + 1) * CC;
    const float* b2 = bn_b + (l * 2 + 1) * CC;
    hipLaunchKernelGGL(mm_kernel, dim3(782), dim3(256), 0, stream, X, Y, w1, statsA, g1, b1, statsB);
    hipLaunchKernelGGL(seg_kernel, dim3(2048), dim3(256), 0, stream, Y, (const float*)nullptr, H,
                       rp_in, col_in, rp_out, col_out, statsB);
    hipLaunchKernelGGL(mm_kernel, dim3(782), dim3(256), 0, stream, H, Y, w2, statsB, g2, b2, statsA);
    hipLaunchKernelGGL(seg_kernel, dim3(2048), dim3(256), 0, stream, Y, X, X,
                       rp_in, col_in, rp_out, col_out, statsA);
    hipLaunchKernelGGL(gather_sel_kernel, dim3(KSEL * CC / 256), dim3(256), 0, stream,
                       X, indices, sel, 2 * CC + l * CC);
  }

  hipLaunchKernelGGL(hidden_kernel, dim3(1024), dim3(64), 0, stream, sel, hw, hb, h1);
  hipLaunchKernelGGL(out_kernel, dim3(KSEL / 4), dim3(256), 0, stream, h1, ow, ob, logits);
  hipLaunchKernelGGL(softmax_kernel, dim3(1), dim3(512), 0, stream, logits, out);
}